// Round 7
// baseline (2294.093 us; speedup 1.0000x reference)
//
#include <hip/hip_runtime.h>

#define ODIM 128          // OUT_DIM
#define BROWS 128         // rows per bucket
#define NBMAX 512         // max buckets (N/128 = 391 for N=50000)
#define TILE 4096         // edges per partition tile

typedef unsigned u32;

// ---------------- bucket histogram (both matrices) ----------------

__global__ __launch_bounds__(256) void hist_buckets(
    const int* __restrict__ xr, int nx, const int* __restrict__ ar, int na,
    int* __restrict__ ghX, int* __restrict__ ghA) {
  __shared__ int lh[2 * NBMAX];
  for (int i = threadIdx.x; i < 2 * NBMAX; i += 256) lh[i] = 0;
  __syncthreads();
  int total = nx + na;
  for (int i = blockIdx.x * 256 + threadIdx.x; i < total; i += gridDim.x * 256) {
    if (i < nx) atomicAdd(&lh[xr[i] >> 7], 1);
    else        atomicAdd(&lh[NBMAX + (ar[i - nx] >> 7)], 1);
  }
  __syncthreads();
  for (int b = threadIdx.x; b < NBMAX; b += 256) {
    if (lh[b])         atomicAdd(&ghX[b], lh[b]);
    if (lh[NBMAX + b]) atomicAdd(&ghA[b], lh[NBMAX + b]);
  }
}

// ---------------- bucket scan (block 0: X, block 1: A) ----------------

__global__ __launch_bounds__(NBMAX) void scan_buckets(
    int* __restrict__ ghX, int* __restrict__ baseX, int* __restrict__ curX,
    int* __restrict__ ghA, int* __restrict__ baseA, int* __restrict__ curA,
    int nb) {
  int* gh   = blockIdx.x ? ghA   : ghX;
  int* base = blockIdx.x ? baseA : baseX;
  int* cur  = blockIdx.x ? curA  : curX;
  __shared__ int s[NBMAX];
  int tid = threadIdx.x;
  int v = (tid < nb) ? gh[tid] : 0;
  s[tid] = v;
  __syncthreads();
  for (int off = 1; off < NBMAX; off <<= 1) {
    int t = (tid >= off) ? s[tid - off] : 0;
    __syncthreads();
    s[tid] += t;
    __syncthreads();
  }
  int excl = s[tid] - v;
  if (tid < nb) { base[tid] = excl; cur[tid] = excl; }
  if (tid == NBMAX - 1) base[nb] = s[tid];
}

// ---------------- tile partition: counting-sort by bucket, coalesced runs ----

__global__ __launch_bounds__(256) void partition_kernel(
    const int* __restrict__ rows, const int* __restrict__ cols,
    const float* __restrict__ vals, int nnz,
    int* __restrict__ gcur, uint2* __restrict__ outbuf) {
  __shared__ uint2 pay[TILE];            // 32KB packed (meta, val)
  __shared__ unsigned short bkt[TILE];   // 8KB bucket id per edge
  __shared__ unsigned short perm[TILE];  // 8KB sorted_pos -> tile idx
  __shared__ int hist[NBMAX];
  __shared__ int scn[NBMAX];
  __shared__ int cur[NBMAX];
  __shared__ int gbase[NBMAX];
  __shared__ int part[256];

  int tid = threadIdx.x;
  int tbase = blockIdx.x * TILE;
  int cnt = nnz - tbase; if (cnt > TILE) cnt = TILE;

  for (int b = tid; b < NBMAX; b += 256) hist[b] = 0;
  __syncthreads();

  // load + local hist
  for (int j = tid; j < cnt; j += 256) {
    int r = rows[tbase + j];
    int c = cols[tbase + j];
    float v = vals[tbase + j];
    unsigned b = (unsigned)r >> 7;
    bkt[j] = (unsigned short)b;
    pay[j] = make_uint2(((unsigned)(r & 127) << 17) | (unsigned)c, __float_as_uint(v));
    atomicAdd(&hist[b], 1);
  }
  __syncthreads();

  // exclusive scan of hist[0..NBMAX) with 256 threads (2 entries each)
  int h0 = hist[2 * tid], h1 = hist[2 * tid + 1];
  int psum = h0 + h1;
  part[tid] = psum;
  __syncthreads();
  for (int off = 1; off < 256; off <<= 1) {
    int t = (tid >= off) ? part[tid - off] : 0;
    __syncthreads();
    part[tid] += t;
    __syncthreads();
  }
  int excl = part[tid] - psum;
  scn[2 * tid] = excl;     scn[2 * tid + 1] = excl + h0;
  cur[2 * tid] = excl;     cur[2 * tid + 1] = excl + h0;
  __syncthreads();

  // place: perm[sorted_pos] = tile idx
  for (int j = tid; j < cnt; j += 256) {
    int pos = atomicAdd(&cur[bkt[j]], 1);
    perm[pos] = (unsigned short)j;
  }
  // reserve global ranges per bucket
  for (int b = tid; b < NBMAX; b += 256) {
    int c = hist[b];
    if (c) gbase[b] = atomicAdd(&gcur[b], c);
  }
  __syncthreads();

  // write out: consecutive sorted positions -> consecutive global slots
  for (int p = tid; p < cnt; p += 256) {
    int j = perm[p];
    int b = bkt[j];
    outbuf[gbase[b] + (p - scn[b])] = pay[j];
  }
}

// ---------------- pulls with LDS fp32 accumulator ----------------

__device__ inline unsigned f2bf(float x) {  // fp32 -> bf16 bits, RNE
  unsigned u = __float_as_uint(x);
  return (u + 0x7fffu + ((u >> 16) & 1u)) >> 16;
}

// xw word layout: word l of node = bf16(dim l) | bf16(dim 64+l) << 16

__global__ __launch_bounds__(512) void pull_x_bucket(
    const int* __restrict__ base, const uint2* __restrict__ buf,
    const float* __restrict__ W, u32* __restrict__ xw, int N) {
  __shared__ float acc[BROWS * ODIM];  // 64KB
  int tid = threadIdx.x;
  int lane = tid & 63, grp = tid >> 6;  // 8 groups of 64
  int b = blockIdx.x;
  int e0 = base[b], ecnt = base[b + 1] - e0;

  for (int i = tid; i < BROWS * ODIM / 4; i += 512)
    ((float4*)acc)[i] = make_float4(0.f, 0.f, 0.f, 0.f);
  __syncthreads();

  for (int k = grp; k < ecnt; k += 64) {  // 8 groups x unroll 8 covers [k, k+64)
    uint2 ed[8]; float w0[8], w1[8]; int idx[8];
#pragma unroll
    for (int u = 0; u < 8; ++u) idx[u] = k + 8 * u;
#pragma unroll
    for (int u = 0; u < 8; ++u) if (idx[u] < ecnt) ed[u] = buf[e0 + idx[u]];
#pragma unroll
    for (int u = 0; u < 8; ++u) if (idx[u] < ecnt) {
      unsigned c = ed[u].x & 0x1FFFFu;
      w0[u] = W[(size_t)c * ODIM + lane];
      w1[u] = W[(size_t)c * ODIM + 64 + lane];
    }
#pragma unroll
    for (int u = 0; u < 8; ++u) if (idx[u] < ecnt) {
      unsigned r7 = ed[u].x >> 17;
      float v = __uint_as_float(ed[u].y);
      atomicAdd(&acc[r7 * ODIM + lane], v * w0[u]);
      atomicAdd(&acc[r7 * ODIM + 64 + lane], v * w1[u]);
    }
  }
  __syncthreads();

  int node0 = b * BROWS;
  for (int r = grp; r < BROWS; r += 8) {
    int node = node0 + r;
    if (node < N)
      xw[(size_t)node * 64 + lane] =
          f2bf(acc[r * ODIM + lane]) | (f2bf(acc[r * ODIM + 64 + lane]) << 16);
  }
}

__global__ __launch_bounds__(512) void pull_a_bucket(
    const int* __restrict__ base, const uint2* __restrict__ buf,
    const u32* __restrict__ xw, float* __restrict__ out, int N) {
  __shared__ float acc[BROWS * ODIM];  // 64KB
  int tid = threadIdx.x;
  int lane = tid & 63, grp = tid >> 6;
  int b = blockIdx.x;
  int e0 = base[b], ecnt = base[b + 1] - e0;

  for (int i = tid; i < BROWS * ODIM / 4; i += 512)
    ((float4*)acc)[i] = make_float4(0.f, 0.f, 0.f, 0.f);
  __syncthreads();

  for (int k = grp; k < ecnt; k += 64) {
    uint2 ed[8]; u32 xg[8]; int idx[8];
#pragma unroll
    for (int u = 0; u < 8; ++u) idx[u] = k + 8 * u;
#pragma unroll
    for (int u = 0; u < 8; ++u) if (idx[u] < ecnt) ed[u] = buf[e0 + idx[u]];
#pragma unroll
    for (int u = 0; u < 8; ++u) if (idx[u] < ecnt) {
      unsigned c = ed[u].x & 0x1FFFFu;
      xg[u] = xw[(size_t)c * 64 + lane];
    }
#pragma unroll
    for (int u = 0; u < 8; ++u) if (idx[u] < ecnt) {
      unsigned r7 = ed[u].x >> 17;
      float v = __uint_as_float(ed[u].y);
      float lo = __uint_as_float(xg[u] << 16);
      float hi = __uint_as_float(xg[u] & 0xffff0000u);
      atomicAdd(&acc[r7 * ODIM + lane], v * lo);
      atomicAdd(&acc[r7 * ODIM + 64 + lane], v * hi);
    }
  }
  __syncthreads();

  int node0 = b * BROWS;
  for (int r = grp; r < BROWS; r += 8) {
    int node = node0 + r;
    if (node < N) {
      out[(size_t)node * ODIM + lane]      = fmaxf(acc[r * ODIM + lane], 0.f);
      out[(size_t)node * ODIM + 64 + lane] = fmaxf(acc[r * ODIM + 64 + lane], 0.f);
    }
  }
}

// ---------------- fallback (atomic push) ----------------

__global__ __launch_bounds__(256) void spmm_scatter(
    const int* __restrict__ rows, const int* __restrict__ cols,
    const float* __restrict__ vals, const float* __restrict__ B,
    float* __restrict__ out, int nnz) {
  int e = blockIdx.x * 2 + (threadIdx.x >> 7);
  int d = threadIdx.x & (ODIM - 1);
  if (e >= nnz) return;
  atomicAdd(&out[(size_t)rows[e] * ODIM + d],
            vals[e] * B[(size_t)cols[e] * ODIM + d]);
}

__global__ __launch_bounds__(256) void relu_inplace(float* __restrict__ p, long n4) {
  long i = (long)blockIdx.x * blockDim.x + threadIdx.x;
  long stride = (long)gridDim.x * blockDim.x;
  float4* p4 = (float4*)p;
  for (long j = i; j < n4; j += stride) {
    float4 v = p4[j];
    v.x = fmaxf(v.x, 0.f); v.y = fmaxf(v.y, 0.f);
    v.z = fmaxf(v.z, 0.f); v.w = fmaxf(v.w, 0.f);
    p4[j] = v;
  }
}

extern "C" void kernel_launch(void* const* d_in, const int* in_sizes, int n_in,
                              void* d_out, int out_size, void* d_ws, size_t ws_size,
                              hipStream_t stream) {
  const int*   x_rows   = (const int*)d_in[0];
  const int*   x_cols   = (const int*)d_in[1];
  const float* x_vals   = (const float*)d_in[2];
  const int*   adj_rows = (const int*)d_in[3];
  const int*   adj_cols = (const int*)d_in[4];
  const float* adj_vals = (const float*)d_in[5];
  const float* W        = (const float*)d_in[6];

  const int nnz_x   = in_sizes[0];
  const int nnz_adj = in_sizes[3];
  const int N       = out_size / ODIM;  // 50000
  const int NB      = (N + BROWS - 1) / BROWS;  // 391

  float* out = (float*)d_out;

  // Workspace layout
  char* p = (char*)d_ws;
  u32* xw   = (u32*)p;  p += (size_t)N * 64 * sizeof(u32);   // packed bf16 pairs
  int* ghX  = (int*)p;  p += NBMAX * sizeof(int);
  int* ghA  = (int*)p;  p += NBMAX * sizeof(int);            // adjacent: one memset
  int* baseX= (int*)p;  p += (NBMAX + 1) * sizeof(int);
  int* baseA= (int*)p;  p += (NBMAX + 1) * sizeof(int);
  int* curX = (int*)p;  p += NBMAX * sizeof(int);
  int* curA = (int*)p;  p += NBMAX * sizeof(int);
  p = (char*)(((uintptr_t)p + 255) & ~(uintptr_t)255);
  uint2* bufX = (uint2*)p; p += (size_t)nnz_x * sizeof(uint2);
  uint2* bufA = (uint2*)p; p += (size_t)nnz_adj * sizeof(uint2);
  size_t need = (size_t)(p - (char*)d_ws);

  if (ws_size < need || NB > NBMAX) {
    // Fallback: atomic push with fp32 xw at start of ws.
    float* xwf = (float*)d_ws;
    const size_t out_bytes = (size_t)out_size * sizeof(float);
    (void)hipMemsetAsync(xwf, 0, out_bytes, stream);
    (void)hipMemsetAsync(out, 0, out_bytes, stream);
    spmm_scatter<<<(nnz_x + 1) / 2, 256, 0, stream>>>(x_rows, x_cols, x_vals, W, xwf, nnz_x);
    spmm_scatter<<<(nnz_adj + 1) / 2, 256, 0, stream>>>(adj_rows, adj_cols, adj_vals, xwf, out, nnz_adj);
    relu_inplace<<<2048, 256, 0, stream>>>(out, (long)out_size / 4);
    return;
  }

  // zero both bucket hists (contiguous)
  (void)hipMemsetAsync(ghX, 0, 2 * NBMAX * sizeof(int), stream);

  hist_buckets<<<1024, 256, 0, stream>>>(x_rows, nnz_x, adj_rows, nnz_adj, ghX, ghA);
  scan_buckets<<<2, NBMAX, 0, stream>>>(ghX, baseX, curX, ghA, baseA, curA, NB);

  partition_kernel<<<(nnz_x + TILE - 1) / TILE, 256, 0, stream>>>(
      x_rows, x_cols, x_vals, nnz_x, curX, bufX);
  partition_kernel<<<(nnz_adj + TILE - 1) / TILE, 256, 0, stream>>>(
      adj_rows, adj_cols, adj_vals, nnz_adj, curA, bufA);

  pull_x_bucket<<<NB, 512, 0, stream>>>(baseX, bufX, W, xw, N);
  pull_a_bucket<<<NB, 512, 0, stream>>>(baseA, bufA, xw, out, N);
}

// Round 8
// 229.845 us; speedup vs baseline: 9.9810x; 9.9810x over previous
//
#include <hip/hip_runtime.h>

#define ODIM 128          // OUT_DIM
#define BROWS 128         // rows per bucket
#define NBMAX 512         // max buckets (N/128 = 391 for N=50000)
#define TILE 4096         // edges per partition tile
#define CMASK 0x1FFFFu    // low 17 bits of meta = col

typedef unsigned u32;

// ---------------- bucket histogram (both matrices) ----------------

__global__ __launch_bounds__(256) void hist_buckets(
    const int* __restrict__ xr, int nx, const int* __restrict__ ar, int na,
    int* __restrict__ ghX, int* __restrict__ ghA) {
  __shared__ int lh[2 * NBMAX];
  for (int i = threadIdx.x; i < 2 * NBMAX; i += 256) lh[i] = 0;
  __syncthreads();
  int total = nx + na;
  for (int i = blockIdx.x * 256 + threadIdx.x; i < total; i += gridDim.x * 256) {
    if (i < nx) atomicAdd(&lh[xr[i] >> 7], 1);
    else        atomicAdd(&lh[NBMAX + (ar[i - nx] >> 7)], 1);
  }
  __syncthreads();
  for (int b = threadIdx.x; b < NBMAX; b += 256) {
    if (lh[b])         atomicAdd(&ghX[b], lh[b]);
    if (lh[NBMAX + b]) atomicAdd(&ghA[b], lh[NBMAX + b]);
  }
}

// ---------------- bucket scan (block 0: X, block 1: A) ----------------

__global__ __launch_bounds__(NBMAX) void scan_buckets(
    int* __restrict__ ghX, int* __restrict__ baseX, int* __restrict__ curX,
    int* __restrict__ ghA, int* __restrict__ baseA, int* __restrict__ curA,
    int nb) {
  int* gh   = blockIdx.x ? ghA   : ghX;
  int* base = blockIdx.x ? baseA : baseX;
  int* cur  = blockIdx.x ? curA  : curX;
  __shared__ int s[NBMAX];
  int tid = threadIdx.x;
  int v = (tid < nb) ? gh[tid] : 0;
  s[tid] = v;
  __syncthreads();
  for (int off = 1; off < NBMAX; off <<= 1) {
    int t = (tid >= off) ? s[tid - off] : 0;
    __syncthreads();
    s[tid] += t;
    __syncthreads();
  }
  int excl = s[tid] - v;
  if (tid < nb) { base[tid] = excl; cur[tid] = excl; }
  if (tid == NBMAX - 1) base[nb] = s[tid];
}

// ---------------- pass 1: tile counting-sort into buckets, coalesced runs ----

__global__ __launch_bounds__(256) void partition_kernel(
    const int* __restrict__ rows, const int* __restrict__ cols,
    const float* __restrict__ vals, int nnz,
    int* __restrict__ gcur, uint2* __restrict__ outbuf) {
  __shared__ uint2 pay[TILE];            // 32KB packed (meta, val)
  __shared__ unsigned short bkt[TILE];   // 8KB bucket id per edge
  __shared__ unsigned short perm[TILE];  // 8KB sorted_pos -> tile idx
  __shared__ int hist[NBMAX];
  __shared__ int scn[NBMAX];
  __shared__ int cur[NBMAX];
  __shared__ int gbase[NBMAX];
  __shared__ int part[256];

  int tid = threadIdx.x;
  int tbase = blockIdx.x * TILE;
  int cnt = nnz - tbase; if (cnt > TILE) cnt = TILE;

  for (int b = tid; b < NBMAX; b += 256) hist[b] = 0;
  __syncthreads();

  // load + local hist
  for (int j = tid; j < cnt; j += 256) {
    int r = rows[tbase + j];
    int c = cols[tbase + j];
    float v = vals[tbase + j];
    unsigned b = (unsigned)r >> 7;
    bkt[j] = (unsigned short)b;
    pay[j] = make_uint2(((unsigned)(r & 127) << 17) | (unsigned)c, __float_as_uint(v));
    atomicAdd(&hist[b], 1);
  }
  __syncthreads();

  // exclusive scan of hist[0..NBMAX) with 256 threads (2 entries each)
  int h0 = hist[2 * tid], h1 = hist[2 * tid + 1];
  int psum = h0 + h1;
  part[tid] = psum;
  __syncthreads();
  for (int off = 1; off < 256; off <<= 1) {
    int t = (tid >= off) ? part[tid - off] : 0;
    __syncthreads();
    part[tid] += t;
    __syncthreads();
  }
  int excl = part[tid] - psum;
  scn[2 * tid] = excl;     scn[2 * tid + 1] = excl + h0;
  cur[2 * tid] = excl;     cur[2 * tid + 1] = excl + h0;
  __syncthreads();

  // place: perm[sorted_pos] = tile idx
  for (int j = tid; j < cnt; j += 256) {
    int pos = atomicAdd(&cur[bkt[j]], 1);
    perm[pos] = (unsigned short)j;
  }
  // reserve global ranges per bucket
  for (int b = tid; b < NBMAX; b += 256) {
    int c = hist[b];
    if (c) gbase[b] = atomicAdd(&gcur[b], c);
  }
  __syncthreads();

  // write out: consecutive sorted positions -> consecutive global slots
  for (int p = tid; p < cnt; p += 256) {
    int j = perm[p];
    int b = bkt[j];
    outbuf[gbase[b] + (p - scn[b])] = pay[j];
  }
}

// ---------------- pass 2: per-bucket exact row sort + rowptr ----------------
// One block per bucket. Scatter confined to the bucket's private contiguous
// range -> single-XCD L2 write-combining, writeback ~= payload.

__global__ __launch_bounds__(256) void bucket_sort(
    const int* __restrict__ base, const uint2* __restrict__ bufin,
    uint2* __restrict__ bufout, int* __restrict__ rowptr, int N) {
  __shared__ int hist[BROWS], scn[BROWS], cur[BROWS];
  int tid = threadIdx.x;
  int b = blockIdx.x;
  int e0 = base[b], ecnt = base[b + 1] - e0;

  if (tid < BROWS) hist[tid] = 0;
  __syncthreads();
  for (int j = tid; j < ecnt; j += 256)
    atomicAdd(&hist[bufin[e0 + j].x >> 17], 1);
  __syncthreads();

  // inclusive scan over 128 bins (tid<128 active; whole-block barriers)
  int v = (tid < BROWS) ? hist[tid] : 0;
  if (tid < BROWS) scn[tid] = v;
  __syncthreads();
  for (int off = 1; off < BROWS; off <<= 1) {
    int t = (tid < BROWS && tid >= off) ? scn[tid - off] : 0;
    __syncthreads();
    if (tid < BROWS) scn[tid] += t;
    __syncthreads();
  }
  if (tid < BROWS) {
    int excl = scn[tid] - v;
    cur[tid] = excl;
    int node = b * BROWS + tid;
    if (node <= N) rowptr[node] = e0 + excl;  // node==N lands here too (all-zero tail rows)
  }
  __syncthreads();

  for (int j = tid; j < ecnt; j += 256) {
    uint2 e = bufin[e0 + j];
    int pos = atomicAdd(&cur[e.x >> 17], 1);
    bufout[e0 + pos] = e;
  }
}

// ---------------- pulls (wave per row, register accumulate) ----------------

__device__ inline unsigned f2bf(float x) {  // fp32 -> bf16 bits, RNE
  unsigned u = __float_as_uint(x);
  return (u + 0x7fffu + ((u >> 16) & 1u)) >> 16;
}

// xw[r] = sum_e val_e * W[col_e]  (W fp32, L2-resident; xw stored bf16-packed)
__global__ __launch_bounds__(256) void pull_x(
    const int* __restrict__ rowptr, const uint2* __restrict__ cv,
    const float* __restrict__ W, unsigned* __restrict__ xw, int nrows) {
  int lane = threadIdx.x & 63;
  int r = blockIdx.x * 4 + (threadIdx.x >> 6);
  if (r >= nrows) return;
  int e = rowptr[r], end = rowptr[r + 1];
  const float2* W2 = (const float2*)W;
  float a0 = 0.f, a1 = 0.f, b0 = 0.f, b1 = 0.f;
  for (; e + 1 < end; e += 2) {
    uint2 ca = cv[e];
    uint2 cb = cv[e + 1];
    float2 wa = W2[(size_t)(ca.x & CMASK) * 64 + lane];
    float2 wb = W2[(size_t)(cb.x & CMASK) * 64 + lane];
    float va = __uint_as_float(ca.y), vb = __uint_as_float(cb.y);
    a0 += va * wa.x; a1 += va * wa.y;
    b0 += vb * wb.x; b1 += vb * wb.y;
  }
  if (e < end) {
    uint2 ca = cv[e];
    float2 wa = W2[(size_t)(ca.x & CMASK) * 64 + lane];
    float va = __uint_as_float(ca.y);
    a0 += va * wa.x; a1 += va * wa.y;
  }
  xw[(size_t)r * 64 + lane] = f2bf(a0 + b0) | (f2bf(a1 + b1) << 16);
}

// out[r] = relu( sum_e val_e * xw[col_e] )  (xw bf16-packed, out fp32)
// 4-edge unroll: 4 independent 256B gathers in flight per wave.
__global__ __launch_bounds__(256) void pull_a(
    const int* __restrict__ rowptr, const uint2* __restrict__ cv,
    const unsigned* __restrict__ xw, float2* __restrict__ out, int nrows) {
  int lane = threadIdx.x & 63;
  int r = blockIdx.x * 4 + (threadIdx.x >> 6);
  if (r >= nrows) return;
  int e = rowptr[r], end = rowptr[r + 1];
  float a0 = 0.f, a1 = 0.f, b0 = 0.f, b1 = 0.f;
  float c0 = 0.f, c1 = 0.f, d0 = 0.f, d1 = 0.f;
  for (; e + 3 < end; e += 4) {
    uint2 ca = cv[e];
    uint2 cb = cv[e + 1];
    uint2 cc = cv[e + 2];
    uint2 cd = cv[e + 3];
    unsigned ua = xw[(size_t)(ca.x & CMASK) * 64 + lane];
    unsigned ub = xw[(size_t)(cb.x & CMASK) * 64 + lane];
    unsigned uc = xw[(size_t)(cc.x & CMASK) * 64 + lane];
    unsigned ud = xw[(size_t)(cd.x & CMASK) * 64 + lane];
    float va = __uint_as_float(ca.y), vb = __uint_as_float(cb.y);
    float vc = __uint_as_float(cc.y), vd = __uint_as_float(cd.y);
    a0 += va * __uint_as_float(ua << 16);
    a1 += va * __uint_as_float(ua & 0xffff0000u);
    b0 += vb * __uint_as_float(ub << 16);
    b1 += vb * __uint_as_float(ub & 0xffff0000u);
    c0 += vc * __uint_as_float(uc << 16);
    c1 += vc * __uint_as_float(uc & 0xffff0000u);
    d0 += vd * __uint_as_float(ud << 16);
    d1 += vd * __uint_as_float(ud & 0xffff0000u);
  }
  for (; e < end; ++e) {
    uint2 ca = cv[e];
    unsigned ua = xw[(size_t)(ca.x & CMASK) * 64 + lane];
    float va = __uint_as_float(ca.y);
    a0 += va * __uint_as_float(ua << 16);
    a1 += va * __uint_as_float(ua & 0xffff0000u);
  }
  float o0 = fmaxf((a0 + b0) + (c0 + d0), 0.f);
  float o1 = fmaxf((a1 + b1) + (c1 + d1), 0.f);
  out[(size_t)r * 64 + lane] = make_float2(o0, o1);
}

// ---------------- fallback (atomic push) ----------------

__global__ __launch_bounds__(256) void spmm_scatter(
    const int* __restrict__ rows, const int* __restrict__ cols,
    const float* __restrict__ vals, const float* __restrict__ B,
    float* __restrict__ out, int nnz) {
  int e = blockIdx.x * 2 + (threadIdx.x >> 7);
  int d = threadIdx.x & (ODIM - 1);
  if (e >= nnz) return;
  atomicAdd(&out[(size_t)rows[e] * ODIM + d],
            vals[e] * B[(size_t)cols[e] * ODIM + d]);
}

__global__ __launch_bounds__(256) void relu_inplace(float* __restrict__ p, long n4) {
  long i = (long)blockIdx.x * blockDim.x + threadIdx.x;
  long stride = (long)gridDim.x * blockDim.x;
  float4* p4 = (float4*)p;
  for (long j = i; j < n4; j += stride) {
    float4 v = p4[j];
    v.x = fmaxf(v.x, 0.f); v.y = fmaxf(v.y, 0.f);
    v.z = fmaxf(v.z, 0.f); v.w = fmaxf(v.w, 0.f);
    p4[j] = v;
  }
}

extern "C" void kernel_launch(void* const* d_in, const int* in_sizes, int n_in,
                              void* d_out, int out_size, void* d_ws, size_t ws_size,
                              hipStream_t stream) {
  const int*   x_rows   = (const int*)d_in[0];
  const int*   x_cols   = (const int*)d_in[1];
  const float* x_vals   = (const float*)d_in[2];
  const int*   adj_rows = (const int*)d_in[3];
  const int*   adj_cols = (const int*)d_in[4];
  const float* adj_vals = (const float*)d_in[5];
  const float* W        = (const float*)d_in[6];

  const int nnz_x   = in_sizes[0];
  const int nnz_adj = in_sizes[3];
  const int N       = out_size / ODIM;        // 50000
  const int NB      = (N + BROWS - 1) / BROWS; // 391

  float* out = (float*)d_out;

  // Workspace layout. bufP is the pass-1 ping buffer for BOTH matrices and is
  // later reused as xw (sequential stream: last read of bufP is bucket_sort(A),
  // which completes before pull_x writes xw).
  size_t bufP_elems = (size_t)(nnz_x > nnz_adj ? nnz_x : nnz_adj);
  size_t xw_words   = (size_t)N * 64;  // bf16x2-packed, N*256 bytes
  if (bufP_elems * 2 < xw_words) bufP_elems = (xw_words + 1) / 2;

  char* p = (char*)d_ws;
  int* ghX   = (int*)p;  p += NBMAX * sizeof(int);
  int* ghA   = (int*)p;  p += NBMAX * sizeof(int);        // adjacent: one memset
  int* baseX = (int*)p;  p += (NBMAX + 1) * sizeof(int);
  int* baseA = (int*)p;  p += (NBMAX + 1) * sizeof(int);
  int* curX  = (int*)p;  p += NBMAX * sizeof(int);
  int* curA  = (int*)p;  p += NBMAX * sizeof(int);
  int* rpX   = (int*)p;  p += (size_t)(N + 1) * sizeof(int);
  int* rpA   = (int*)p;  p += (size_t)(N + 1) * sizeof(int);
  p = (char*)(((uintptr_t)p + 255) & ~(uintptr_t)255);
  uint2* bufP  = (uint2*)p; p += bufP_elems * sizeof(uint2);
  uint2* bufSX = (uint2*)p; p += (size_t)nnz_x * sizeof(uint2);
  uint2* bufSA = (uint2*)p; p += (size_t)nnz_adj * sizeof(uint2);
  size_t need = (size_t)(p - (char*)d_ws);
  u32* xw = (u32*)bufP;  // alias

  if (ws_size < need || NB > NBMAX) {
    // Fallback: atomic push with fp32 xw at start of ws.
    float* xwf = (float*)d_ws;
    const size_t out_bytes = (size_t)out_size * sizeof(float);
    (void)hipMemsetAsync(xwf, 0, out_bytes, stream);
    (void)hipMemsetAsync(out, 0, out_bytes, stream);
    spmm_scatter<<<(nnz_x + 1) / 2, 256, 0, stream>>>(x_rows, x_cols, x_vals, W, xwf, nnz_x);
    spmm_scatter<<<(nnz_adj + 1) / 2, 256, 0, stream>>>(adj_rows, adj_cols, adj_vals, xwf, out, nnz_adj);
    relu_inplace<<<2048, 256, 0, stream>>>(out, (long)out_size / 4);
    return;
  }

  // zero both bucket hists (contiguous)
  (void)hipMemsetAsync(ghX, 0, 2 * NBMAX * sizeof(int), stream);

  hist_buckets<<<1024, 256, 0, stream>>>(x_rows, nnz_x, adj_rows, nnz_adj, ghX, ghA);
  scan_buckets<<<2, NBMAX, 0, stream>>>(ghX, baseX, curX, ghA, baseA, curA, NB);

  // X: partition -> exact sort (+rowptr)
  partition_kernel<<<(nnz_x + TILE - 1) / TILE, 256, 0, stream>>>(
      x_rows, x_cols, x_vals, nnz_x, curX, bufP);
  bucket_sort<<<NB, 256, 0, stream>>>(baseX, bufP, bufSX, rpX, N);

  // A: partition -> exact sort (+rowptr)   (bufP reused)
  partition_kernel<<<(nnz_adj + TILE - 1) / TILE, 256, 0, stream>>>(
      adj_rows, adj_cols, adj_vals, nnz_adj, curA, bufP);
  bucket_sort<<<NB, 256, 0, stream>>>(baseA, bufP, bufSA, rpA, N);

  // Step 1: xw = X @ W  (fp32 accumulate, bf16 store; xw overwrites bufP)
  pull_x<<<(N + 3) / 4, 256, 0, stream>>>(rpX, bufSX, W, xw, N);

  // Step 2: out = relu(A @ xw)
  pull_a<<<(N + 3) / 4, 256, 0, stream>>>(rpA, bufSA, xw, (float2*)out, N);
}

// Round 9
// 195.068 us; speedup vs baseline: 11.7605x; 1.1783x over previous
//
#include <hip/hip_runtime.h>

#define ODIM 128          // OUT_DIM
#define BROWS 128         // rows per bucket
#define NBMAX 512         // max buckets (N/128 = 391 for N=50000)
#define TILE 4096         // edges per partition tile
#define CMASK 0x1FFFFu    // low 17 bits of meta = col

typedef unsigned u32;

// ---------------- bucket histogram (both matrices) ----------------

__global__ __launch_bounds__(256) void hist_buckets(
    const int* __restrict__ xr, int nx, const int* __restrict__ ar, int na,
    int* __restrict__ ghX, int* __restrict__ ghA) {
  __shared__ int lh[2 * NBMAX];
  for (int i = threadIdx.x; i < 2 * NBMAX; i += 256) lh[i] = 0;
  __syncthreads();
  int total = nx + na;
  for (int i = blockIdx.x * 256 + threadIdx.x; i < total; i += gridDim.x * 256) {
    if (i < nx) atomicAdd(&lh[xr[i] >> 7], 1);
    else        atomicAdd(&lh[NBMAX + (ar[i - nx] >> 7)], 1);
  }
  __syncthreads();
  for (int b = threadIdx.x; b < NBMAX; b += 256) {
    if (lh[b])         atomicAdd(&ghX[b], lh[b]);
    if (lh[NBMAX + b]) atomicAdd(&ghA[b], lh[NBMAX + b]);
  }
}

// ---------------- bucket scan (block 0: X, block 1: A) ----------------

__global__ __launch_bounds__(NBMAX) void scan_buckets(
    int* __restrict__ ghX, int* __restrict__ baseX, int* __restrict__ curX,
    int* __restrict__ ghA, int* __restrict__ baseA, int* __restrict__ curA,
    int nb) {
  int* gh   = blockIdx.x ? ghA   : ghX;
  int* base = blockIdx.x ? baseA : baseX;
  int* cur  = blockIdx.x ? curA  : curX;
  __shared__ int s[NBMAX];
  int tid = threadIdx.x;
  int v = (tid < nb) ? gh[tid] : 0;
  s[tid] = v;
  __syncthreads();
  for (int off = 1; off < NBMAX; off <<= 1) {
    int t = (tid >= off) ? s[tid - off] : 0;
    __syncthreads();
    s[tid] += t;
    __syncthreads();
  }
  int excl = s[tid] - v;
  if (tid < nb) { base[tid] = excl; cur[tid] = excl; }
  if (tid == NBMAX - 1) base[nb] = s[tid];
}

// ---- pass 1: tile counting-sort into buckets (X and A fused in one grid) ----

__global__ __launch_bounds__(256) void partition_both(
    const int* __restrict__ xr, const int* __restrict__ xc,
    const float* __restrict__ xv, int nx, int ntX,
    int* __restrict__ curX, uint2* __restrict__ outX,
    const int* __restrict__ ar, const int* __restrict__ ac,
    const float* __restrict__ av, int na,
    int* __restrict__ curA, uint2* __restrict__ outA) {
  __shared__ uint2 pay[TILE];            // 32KB packed (meta, val)
  __shared__ unsigned short bkt[TILE];   // 8KB
  __shared__ unsigned short perm[TILE];  // 8KB
  __shared__ int hist[NBMAX];
  __shared__ int scn[NBMAX];
  __shared__ int cur[NBMAX];
  __shared__ int gbase[NBMAX];
  __shared__ int part[256];

  const int* rows; const int* cols; const float* vals;
  int nnz; int* gcur; uint2* outbuf; int tile;
  if ((int)blockIdx.x < ntX) {
    rows = xr; cols = xc; vals = xv; nnz = nx; gcur = curX; outbuf = outX;
    tile = blockIdx.x;
  } else {
    rows = ar; cols = ac; vals = av; nnz = na; gcur = curA; outbuf = outA;
    tile = blockIdx.x - ntX;
  }

  int tid = threadIdx.x;
  int tbase = tile * TILE;
  int cnt = nnz - tbase; if (cnt > TILE) cnt = TILE;

  for (int b = tid; b < NBMAX; b += 256) hist[b] = 0;
  __syncthreads();

  // load + local hist
  for (int j = tid; j < cnt; j += 256) {
    int r = rows[tbase + j];
    int c = cols[tbase + j];
    float v = vals[tbase + j];
    unsigned b = (unsigned)r >> 7;
    bkt[j] = (unsigned short)b;
    pay[j] = make_uint2(((unsigned)(r & 127) << 17) | (unsigned)c, __float_as_uint(v));
    atomicAdd(&hist[b], 1);
  }
  __syncthreads();

  // exclusive scan of hist[0..NBMAX) with 256 threads (2 entries each)
  int h0 = hist[2 * tid], h1 = hist[2 * tid + 1];
  int psum = h0 + h1;
  part[tid] = psum;
  __syncthreads();
  for (int off = 1; off < 256; off <<= 1) {
    int t = (tid >= off) ? part[tid - off] : 0;
    __syncthreads();
    part[tid] += t;
    __syncthreads();
  }
  int excl = part[tid] - psum;
  scn[2 * tid] = excl;     scn[2 * tid + 1] = excl + h0;
  cur[2 * tid] = excl;     cur[2 * tid + 1] = excl + h0;
  __syncthreads();

  // place: perm[sorted_pos] = tile idx
  for (int j = tid; j < cnt; j += 256) {
    int pos = atomicAdd(&cur[bkt[j]], 1);
    perm[pos] = (unsigned short)j;
  }
  // reserve global ranges per bucket
  for (int b = tid; b < NBMAX; b += 256) {
    int c = hist[b];
    if (c) gbase[b] = atomicAdd(&gcur[b], c);
  }
  __syncthreads();

  // write out: consecutive sorted positions -> consecutive global slots
  for (int p = tid; p < cnt; p += 256) {
    int j = perm[p];
    int b = bkt[j];
    outbuf[gbase[b] + (p - scn[b])] = pay[j];
  }
}

// ---- pass 2: per-bucket exact row sort + rowptr (X and A fused) ----

__global__ __launch_bounds__(256) void bucket_sort_both(
    int nbX,
    const int* __restrict__ baseX, const uint2* __restrict__ binX,
    uint2* __restrict__ boutX, int* __restrict__ rpX,
    const int* __restrict__ baseA, const uint2* __restrict__ binA,
    uint2* __restrict__ boutA, int* __restrict__ rpA, int N) {
  __shared__ int hist[BROWS], scn[BROWS], cur[BROWS];
  const int* base; const uint2* bufin; uint2* bufout; int* rowptr; int b;
  if ((int)blockIdx.x < nbX) {
    base = baseX; bufin = binX; bufout = boutX; rowptr = rpX; b = blockIdx.x;
  } else {
    base = baseA; bufin = binA; bufout = boutA; rowptr = rpA; b = blockIdx.x - nbX;
  }
  int tid = threadIdx.x;
  int e0 = base[b], ecnt = base[b + 1] - e0;

  if (tid < BROWS) hist[tid] = 0;
  __syncthreads();
  for (int j = tid; j < ecnt; j += 256)
    atomicAdd(&hist[bufin[e0 + j].x >> 17], 1);
  __syncthreads();

  int v = (tid < BROWS) ? hist[tid] : 0;
  if (tid < BROWS) scn[tid] = v;
  __syncthreads();
  for (int off = 1; off < BROWS; off <<= 1) {
    int t = (tid < BROWS && tid >= off) ? scn[tid - off] : 0;
    __syncthreads();
    if (tid < BROWS) scn[tid] += t;
    __syncthreads();
  }
  if (tid < BROWS) {
    int excl = scn[tid] - v;
    cur[tid] = excl;
    int node = b * BROWS + tid;
    if (node <= N) rowptr[node] = e0 + excl;
  }
  __syncthreads();

  for (int j = tid; j < ecnt; j += 256) {
    uint2 e = bufin[e0 + j];
    int pos = atomicAdd(&cur[e.x >> 17], 1);
    bufout[e0 + pos] = e;
  }
}

// ---------------- pulls (wave per row, register accumulate) ----------------

__device__ inline unsigned f2bf(float x) {  // fp32 -> bf16 bits, RNE
  unsigned u = __float_as_uint(x);
  return (u + 0x7fffu + ((u >> 16) & 1u)) >> 16;
}

// xw[r] = sum_e val_e * W[col_e]  (W fp32, L2-resident; xw stored bf16-packed)
__global__ __launch_bounds__(256) void pull_x(
    const int* __restrict__ rowptr, const uint2* __restrict__ cv,
    const float* __restrict__ W, unsigned* __restrict__ xw, int nrows) {
  int lane = threadIdx.x & 63;
  int r = blockIdx.x * 4 + (threadIdx.x >> 6);
  if (r >= nrows) return;
  int e = rowptr[r], end = rowptr[r + 1];
  const float2* W2 = (const float2*)W;
  float a0 = 0.f, a1 = 0.f, b0 = 0.f, b1 = 0.f;
  float c0 = 0.f, c1 = 0.f, d0 = 0.f, d1 = 0.f;
  for (; e + 3 < end; e += 4) {
    uint2 ea = cv[e], eb = cv[e + 1], ec = cv[e + 2], ed = cv[e + 3];
    float2 wa = W2[(size_t)(ea.x & CMASK) * 64 + lane];
    float2 wb = W2[(size_t)(eb.x & CMASK) * 64 + lane];
    float2 wc = W2[(size_t)(ec.x & CMASK) * 64 + lane];
    float2 wd = W2[(size_t)(ed.x & CMASK) * 64 + lane];
    float va = __uint_as_float(ea.y), vb = __uint_as_float(eb.y);
    float vc = __uint_as_float(ec.y), vd = __uint_as_float(ed.y);
    a0 += va * wa.x; a1 += va * wa.y;
    b0 += vb * wb.x; b1 += vb * wb.y;
    c0 += vc * wc.x; c1 += vc * wc.y;
    d0 += vd * wd.x; d1 += vd * wd.y;
  }
  for (; e < end; ++e) {
    uint2 ea = cv[e];
    float2 wa = W2[(size_t)(ea.x & CMASK) * 64 + lane];
    float va = __uint_as_float(ea.y);
    a0 += va * wa.x; a1 += va * wa.y;
  }
  float o0 = (a0 + b0) + (c0 + d0);
  float o1 = (a1 + b1) + (c1 + d1);
  xw[(size_t)r * 64 + lane] = f2bf(o0) | (f2bf(o1) << 16);
}

// out[r] = relu( sum_e val_e * xw[col_e] )  (xw bf16-packed, out fp32)
// 8-edge unroll: 8 independent 256B gathers in flight per wave.
__global__ __launch_bounds__(256) void pull_a(
    const int* __restrict__ rowptr, const uint2* __restrict__ cv,
    const unsigned* __restrict__ xw, float2* __restrict__ out, int nrows) {
  int lane = threadIdx.x & 63;
  int r = blockIdx.x * 4 + (threadIdx.x >> 6);
  if (r >= nrows) return;
  int e = rowptr[r], end = rowptr[r + 1];
  float acc0[8], acc1[8];
#pragma unroll
  for (int u = 0; u < 8; ++u) { acc0[u] = 0.f; acc1[u] = 0.f; }
  for (; e + 7 < end; e += 8) {
    uint2 ed[8]; unsigned xg[8];
#pragma unroll
    for (int u = 0; u < 8; ++u) ed[u] = cv[e + u];
#pragma unroll
    for (int u = 0; u < 8; ++u)
      xg[u] = xw[(size_t)(ed[u].x & CMASK) * 64 + lane];
#pragma unroll
    for (int u = 0; u < 8; ++u) {
      float v = __uint_as_float(ed[u].y);
      acc0[u] += v * __uint_as_float(xg[u] << 16);
      acc1[u] += v * __uint_as_float(xg[u] & 0xffff0000u);
    }
  }
  for (; e + 1 < end; e += 2) {
    uint2 ea = cv[e], eb = cv[e + 1];
    unsigned ua = xw[(size_t)(ea.x & CMASK) * 64 + lane];
    unsigned ub = xw[(size_t)(eb.x & CMASK) * 64 + lane];
    float va = __uint_as_float(ea.y), vb = __uint_as_float(eb.y);
    acc0[0] += va * __uint_as_float(ua << 16);
    acc1[0] += va * __uint_as_float(ua & 0xffff0000u);
    acc0[1] += vb * __uint_as_float(ub << 16);
    acc1[1] += vb * __uint_as_float(ub & 0xffff0000u);
  }
  if (e < end) {
    uint2 ea = cv[e];
    unsigned ua = xw[(size_t)(ea.x & CMASK) * 64 + lane];
    float va = __uint_as_float(ea.y);
    acc0[2] += va * __uint_as_float(ua << 16);
    acc1[2] += va * __uint_as_float(ua & 0xffff0000u);
  }
  float o0 = ((acc0[0] + acc0[1]) + (acc0[2] + acc0[3])) +
             ((acc0[4] + acc0[5]) + (acc0[6] + acc0[7]));
  float o1 = ((acc1[0] + acc1[1]) + (acc1[2] + acc1[3])) +
             ((acc1[4] + acc1[5]) + (acc1[6] + acc1[7]));
  out[(size_t)r * 64 + lane] = make_float2(fmaxf(o0, 0.f), fmaxf(o1, 0.f));
}

// ---------------- fallback (atomic push) ----------------

__global__ __launch_bounds__(256) void spmm_scatter(
    const int* __restrict__ rows, const int* __restrict__ cols,
    const float* __restrict__ vals, const float* __restrict__ B,
    float* __restrict__ out, int nnz) {
  int e = blockIdx.x * 2 + (threadIdx.x >> 7);
  int d = threadIdx.x & (ODIM - 1);
  if (e >= nnz) return;
  atomicAdd(&out[(size_t)rows[e] * ODIM + d],
            vals[e] * B[(size_t)cols[e] * ODIM + d]);
}

__global__ __launch_bounds__(256) void relu_inplace(float* __restrict__ p, long n4) {
  long i = (long)blockIdx.x * blockDim.x + threadIdx.x;
  long stride = (long)gridDim.x * blockDim.x;
  float4* p4 = (float4*)p;
  for (long j = i; j < n4; j += stride) {
    float4 v = p4[j];
    v.x = fmaxf(v.x, 0.f); v.y = fmaxf(v.y, 0.f);
    v.z = fmaxf(v.z, 0.f); v.w = fmaxf(v.w, 0.f);
    p4[j] = v;
  }
}

extern "C" void kernel_launch(void* const* d_in, const int* in_sizes, int n_in,
                              void* d_out, int out_size, void* d_ws, size_t ws_size,
                              hipStream_t stream) {
  const int*   x_rows   = (const int*)d_in[0];
  const int*   x_cols   = (const int*)d_in[1];
  const float* x_vals   = (const float*)d_in[2];
  const int*   adj_rows = (const int*)d_in[3];
  const int*   adj_cols = (const int*)d_in[4];
  const float* adj_vals = (const float*)d_in[5];
  const float* W        = (const float*)d_in[6];

  const int nnz_x   = in_sizes[0];
  const int nnz_adj = in_sizes[3];
  const int N       = out_size / ODIM;         // 50000
  const int NB      = (N + BROWS - 1) / BROWS;  // 391
  const int ntX     = (nnz_x + TILE - 1) / TILE;
  const int ntA     = (nnz_adj + TILE - 1) / TILE;

  float* out = (float*)d_out;

  // Common control block
  char* p = (char*)d_ws;
  int* ghX   = (int*)p;  p += NBMAX * sizeof(int);
  int* ghA   = (int*)p;  p += NBMAX * sizeof(int);        // adjacent: one memset
  int* baseX = (int*)p;  p += (NBMAX + 1) * sizeof(int);
  int* baseA = (int*)p;  p += (NBMAX + 1) * sizeof(int);
  int* curX  = (int*)p;  p += NBMAX * sizeof(int);
  int* curA  = (int*)p;  p += NBMAX * sizeof(int);
  int* rpX   = (int*)p;  p += (size_t)(N + 1) * sizeof(int);
  int* rpA   = (int*)p;  p += (size_t)(N + 1) * sizeof(int);
  p = (char*)(((uintptr_t)p + 255) & ~(uintptr_t)255);
  char* bufs = p;

  const size_t xw_bytes = (size_t)N * 64 * sizeof(u32);

  // --- Fused layout: separate ping buffers for X and A (one partition launch).
  // xw aliases bufPX..bufPA (dead after bucket_sort_both).
  {
    char* q = bufs;
    uint2* bufPX = (uint2*)q; q += (size_t)nnz_x * sizeof(uint2);
    uint2* bufPA = (uint2*)q; q += (size_t)nnz_adj * sizeof(uint2);
    uint2* bufSX = (uint2*)q; q += (size_t)nnz_x * sizeof(uint2);
    uint2* bufSA = (uint2*)q; q += (size_t)nnz_adj * sizeof(uint2);
    size_t need = (size_t)(q - (char*)d_ws);
    bool xw_fits = xw_bytes <= ((size_t)nnz_x + nnz_adj) * sizeof(uint2);
    if (ws_size >= need && NB <= NBMAX && xw_fits) {
      u32* xw = (u32*)bufPX;
      (void)hipMemsetAsync(ghX, 0, 2 * NBMAX * sizeof(int), stream);
      hist_buckets<<<1024, 256, 0, stream>>>(x_rows, nnz_x, adj_rows, nnz_adj, ghX, ghA);
      scan_buckets<<<2, NBMAX, 0, stream>>>(ghX, baseX, curX, ghA, baseA, curA, NB);
      partition_both<<<ntX + ntA, 256, 0, stream>>>(
          x_rows, x_cols, x_vals, nnz_x, ntX, curX, bufPX,
          adj_rows, adj_cols, adj_vals, nnz_adj, curA, bufPA);
      bucket_sort_both<<<2 * NB, 256, 0, stream>>>(
          NB, baseX, bufPX, bufSX, rpX, baseA, bufPA, bufSA, rpA, N);
      pull_x<<<(N + 3) / 4, 256, 0, stream>>>(rpX, bufSX, W, xw, N);
      pull_a<<<(N + 3) / 4, 256, 0, stream>>>(rpA, bufSA, xw, (float2*)out, N);
      return;
    }
  }

  // --- Sequential layout (round-8 style, shared ping buffer) if ws smaller.
  {
    size_t bufP_elems = (size_t)(nnz_x > nnz_adj ? nnz_x : nnz_adj);
    if (bufP_elems * sizeof(uint2) < xw_bytes)
      bufP_elems = (xw_bytes + sizeof(uint2) - 1) / sizeof(uint2);
    char* q = bufs;
    uint2* bufP  = (uint2*)q; q += bufP_elems * sizeof(uint2);
    uint2* bufSX = (uint2*)q; q += (size_t)nnz_x * sizeof(uint2);
    uint2* bufSA = (uint2*)q; q += (size_t)nnz_adj * sizeof(uint2);
    size_t need = (size_t)(q - (char*)d_ws);
    if (ws_size >= need && NB <= NBMAX) {
      u32* xw = (u32*)bufP;
      (void)hipMemsetAsync(ghX, 0, 2 * NBMAX * sizeof(int), stream);
      hist_buckets<<<1024, 256, 0, stream>>>(x_rows, nnz_x, adj_rows, nnz_adj, ghX, ghA);
      scan_buckets<<<2, NBMAX, 0, stream>>>(ghX, baseX, curX, ghA, baseA, curA, NB);
      partition_both<<<ntX, 256, 0, stream>>>(
          x_rows, x_cols, x_vals, nnz_x, ntX, curX, bufP,
          adj_rows, adj_cols, adj_vals, nnz_adj, curA, bufP);
      bucket_sort_both<<<NB, 256, 0, stream>>>(
          NB, baseX, bufP, bufSX, rpX, baseA, bufP, bufSA, rpA, N);
      partition_both<<<ntA, 256, 0, stream>>>(
          x_rows, x_cols, x_vals, nnz_x, 0, curX, bufP,
          adj_rows, adj_cols, adj_vals, nnz_adj, curA, bufP);
      bucket_sort_both<<<NB, 256, 0, stream>>>(
          0, baseX, bufP, bufSX, rpX, baseA, bufP, bufSA, rpA, N);
      pull_x<<<(N + 3) / 4, 256, 0, stream>>>(rpX, bufSX, W, xw, N);
      pull_a<<<(N + 3) / 4, 256, 0, stream>>>(rpA, bufSA, xw, (float2*)out, N);
      return;
    }
  }

  // --- Last resort: atomic push (needs only N*ODIM floats).
  {
    float* xwf = (float*)d_ws;
    const size_t out_bytes = (size_t)out_size * sizeof(float);
    (void)hipMemsetAsync(xwf, 0, out_bytes, stream);
    (void)hipMemsetAsync(out, 0, out_bytes, stream);
    spmm_scatter<<<(nnz_x + 1) / 2, 256, 0, stream>>>(x_rows, x_cols, x_vals, W, xwf, nnz_x);
    spmm_scatter<<<(nnz_adj + 1) / 2, 256, 0, stream>>>(adj_rows, adj_cols, adj_vals, xwf, out, nnz_adj);
    relu_inplace<<<2048, 256, 0, stream>>>(out, (long)out_size / 4);
  }
}

// Round 10
// 173.790 us; speedup vs baseline: 13.2004x; 1.1224x over previous
//
#include <hip/hip_runtime.h>

#define ODIM 128          // OUT_DIM
#define BROWS 128         // rows per bucket
#define NBMAX 512         // max buckets (N/128 = 391 for N=50000)
#define TILE 4096         // edges per partition tile
#define CMASK 0x1FFFFu    // low 17 bits of meta = col

typedef unsigned u32;

// ---------------- bucket histogram (both matrices) ----------------

__global__ __launch_bounds__(256) void hist_buckets(
    const int* __restrict__ xr, int nx, const int* __restrict__ ar, int na,
    int* __restrict__ ghX, int* __restrict__ ghA) {
  __shared__ int lh[2 * NBMAX];
  for (int i = threadIdx.x; i < 2 * NBMAX; i += 256) lh[i] = 0;
  __syncthreads();
  int total = nx + na;
  for (int i = blockIdx.x * 256 + threadIdx.x; i < total; i += gridDim.x * 256) {
    if (i < nx) atomicAdd(&lh[xr[i] >> 7], 1);
    else        atomicAdd(&lh[NBMAX + (ar[i - nx] >> 7)], 1);
  }
  __syncthreads();
  for (int b = threadIdx.x; b < NBMAX; b += 256) {
    if (lh[b])         atomicAdd(&ghX[b], lh[b]);
    if (lh[NBMAX + b]) atomicAdd(&ghA[b], lh[NBMAX + b]);
  }
}

// ---------------- bucket scan (block 0: X, block 1: A) ----------------

__global__ __launch_bounds__(NBMAX) void scan_buckets(
    int* __restrict__ ghX, int* __restrict__ baseX, int* __restrict__ curX,
    int* __restrict__ ghA, int* __restrict__ baseA, int* __restrict__ curA,
    int nb) {
  int* gh   = blockIdx.x ? ghA   : ghX;
  int* base = blockIdx.x ? baseA : baseX;
  int* cur  = blockIdx.x ? curA  : curX;
  __shared__ int s[NBMAX];
  int tid = threadIdx.x;
  int v = (tid < nb) ? gh[tid] : 0;
  s[tid] = v;
  __syncthreads();
  for (int off = 1; off < NBMAX; off <<= 1) {
    int t = (tid >= off) ? s[tid - off] : 0;
    __syncthreads();
    s[tid] += t;
    __syncthreads();
  }
  int excl = s[tid] - v;
  if (tid < nb) { base[tid] = excl; cur[tid] = excl; }
  if (tid == NBMAX - 1) base[nb] = s[tid];
}

// ---------------- W -> packed bf16 (word l of row = dims 2l, 2l+1) ----------

__device__ inline unsigned f2bf(float x) {  // fp32 -> bf16 bits, RNE
  unsigned u = __float_as_uint(x);
  return (u + 0x7fffu + ((u >> 16) & 1u)) >> 16;
}

__global__ __launch_bounds__(256) void conv_w(
    const float2* __restrict__ W2, u32* __restrict__ Wbf, int nwords) {
  int i = blockIdx.x * 256 + threadIdx.x;
  if (i >= nwords) return;
  float2 w = W2[i];
  Wbf[i] = f2bf(w.x) | (f2bf(w.y) << 16);
}

// ---- pass 1: tile counting-sort into buckets (X and A fused in one grid) ----

__global__ __launch_bounds__(256) void partition_both(
    const int* __restrict__ xr, const int* __restrict__ xc,
    const float* __restrict__ xv, int nx, int ntX,
    int* __restrict__ curX, uint2* __restrict__ outX,
    const int* __restrict__ ar, const int* __restrict__ ac,
    const float* __restrict__ av, int na,
    int* __restrict__ curA, uint2* __restrict__ outA) {
  __shared__ uint2 pay[TILE];            // 32KB packed (meta, val)
  __shared__ unsigned short bkt[TILE];   // 8KB
  __shared__ unsigned short perm[TILE];  // 8KB
  __shared__ int hist[NBMAX];
  __shared__ int scn[NBMAX];
  __shared__ int cur[NBMAX];
  __shared__ int gbase[NBMAX];
  __shared__ int part[256];

  const int* rows; const int* cols; const float* vals;
  int nnz; int* gcur; uint2* outbuf; int tile;
  if ((int)blockIdx.x < ntX) {
    rows = xr; cols = xc; vals = xv; nnz = nx; gcur = curX; outbuf = outX;
    tile = blockIdx.x;
  } else {
    rows = ar; cols = ac; vals = av; nnz = na; gcur = curA; outbuf = outA;
    tile = blockIdx.x - ntX;
  }

  int tid = threadIdx.x;
  int tbase = tile * TILE;
  int cnt = nnz - tbase; if (cnt > TILE) cnt = TILE;

  for (int b = tid; b < NBMAX; b += 256) hist[b] = 0;
  __syncthreads();

  // load + local hist
  for (int j = tid; j < cnt; j += 256) {
    int r = rows[tbase + j];
    int c = cols[tbase + j];
    float v = vals[tbase + j];
    unsigned b = (unsigned)r >> 7;
    bkt[j] = (unsigned short)b;
    pay[j] = make_uint2(((unsigned)(r & 127) << 17) | (unsigned)c, __float_as_uint(v));
    atomicAdd(&hist[b], 1);
  }
  __syncthreads();

  // exclusive scan of hist[0..NBMAX) with 256 threads (2 entries each)
  int h0 = hist[2 * tid], h1 = hist[2 * tid + 1];
  int psum = h0 + h1;
  part[tid] = psum;
  __syncthreads();
  for (int off = 1; off < 256; off <<= 1) {
    int t = (tid >= off) ? part[tid - off] : 0;
    __syncthreads();
    part[tid] += t;
    __syncthreads();
  }
  int excl = part[tid] - psum;
  scn[2 * tid] = excl;     scn[2 * tid + 1] = excl + h0;
  cur[2 * tid] = excl;     cur[2 * tid + 1] = excl + h0;
  __syncthreads();

  // place: perm[sorted_pos] = tile idx
  for (int j = tid; j < cnt; j += 256) {
    int pos = atomicAdd(&cur[bkt[j]], 1);
    perm[pos] = (unsigned short)j;
  }
  // reserve global ranges per bucket
  for (int b = tid; b < NBMAX; b += 256) {
    int c = hist[b];
    if (c) gbase[b] = atomicAdd(&gcur[b], c);
  }
  __syncthreads();

  // write out: consecutive sorted positions -> consecutive global slots
  for (int p = tid; p < cnt; p += 256) {
    int j = perm[p];
    int b = bkt[j];
    outbuf[gbase[b] + (p - scn[b])] = pay[j];
  }
}

// ---- pass 2: per-bucket exact row sort + rowptr (X and A fused) ----

__global__ __launch_bounds__(256) void bucket_sort_both(
    int nbX,
    const int* __restrict__ baseX, const uint2* __restrict__ binX,
    uint2* __restrict__ boutX, int* __restrict__ rpX,
    const int* __restrict__ baseA, const uint2* __restrict__ binA,
    uint2* __restrict__ boutA, int* __restrict__ rpA, int N) {
  __shared__ int hist[BROWS], scn[BROWS], cur[BROWS];
  const int* base; const uint2* bufin; uint2* bufout; int* rowptr; int b;
  if ((int)blockIdx.x < nbX) {
    base = baseX; bufin = binX; bufout = boutX; rowptr = rpX; b = blockIdx.x;
  } else {
    base = baseA; bufin = binA; bufout = boutA; rowptr = rpA; b = blockIdx.x - nbX;
  }
  int tid = threadIdx.x;
  int e0 = base[b], ecnt = base[b + 1] - e0;

  if (tid < BROWS) hist[tid] = 0;
  __syncthreads();
  for (int j = tid; j < ecnt; j += 256)
    atomicAdd(&hist[bufin[e0 + j].x >> 17], 1);
  __syncthreads();

  int v = (tid < BROWS) ? hist[tid] : 0;
  if (tid < BROWS) scn[tid] = v;
  __syncthreads();
  for (int off = 1; off < BROWS; off <<= 1) {
    int t = (tid < BROWS && tid >= off) ? scn[tid - off] : 0;
    __syncthreads();
    if (tid < BROWS) scn[tid] += t;
    __syncthreads();
  }
  if (tid < BROWS) {
    int excl = scn[tid] - v;
    cur[tid] = excl;
    int node = b * BROWS + tid;
    if (node <= N) rowptr[node] = e0 + excl;
  }
  __syncthreads();

  for (int j = tid; j < ecnt; j += 256) {
    uint2 e = bufin[e0 + j];
    int pos = atomicAdd(&cur[e.x >> 17], 1);
    bufout[e0 + pos] = e;
  }
}

// ---------------- pulls (wave per row, register accumulate) ----------------
// Both pulls gather packed-bf16 u32 rows (256 B/edge) with 8-edge unroll.
// B word l of a row = bf16(dim 2l) | bf16(dim 2l+1)<<16.

// xw[r] = sum_e val_e * Wbf[col_e]   (output packed bf16)
__global__ __launch_bounds__(256) void pull_x(
    const int* __restrict__ rowptr, const uint2* __restrict__ cv,
    const u32* __restrict__ Wbf, unsigned* __restrict__ xw, int nrows) {
  int lane = threadIdx.x & 63;
  int r = blockIdx.x * 4 + (threadIdx.x >> 6);
  if (r >= nrows) return;
  int e = rowptr[r], end = rowptr[r + 1];
  float acc0[8], acc1[8];
#pragma unroll
  for (int u = 0; u < 8; ++u) { acc0[u] = 0.f; acc1[u] = 0.f; }
  for (; e + 7 < end; e += 8) {
    uint2 ed[8]; unsigned xg[8];
#pragma unroll
    for (int u = 0; u < 8; ++u) ed[u] = cv[e + u];
#pragma unroll
    for (int u = 0; u < 8; ++u)
      xg[u] = Wbf[(size_t)(ed[u].x & CMASK) * 64 + lane];
#pragma unroll
    for (int u = 0; u < 8; ++u) {
      float v = __uint_as_float(ed[u].y);
      acc0[u] += v * __uint_as_float(xg[u] << 16);
      acc1[u] += v * __uint_as_float(xg[u] & 0xffff0000u);
    }
  }
  for (; e + 1 < end; e += 2) {
    uint2 ea = cv[e], eb = cv[e + 1];
    unsigned ua = Wbf[(size_t)(ea.x & CMASK) * 64 + lane];
    unsigned ub = Wbf[(size_t)(eb.x & CMASK) * 64 + lane];
    float va = __uint_as_float(ea.y), vb = __uint_as_float(eb.y);
    acc0[0] += va * __uint_as_float(ua << 16);
    acc1[0] += va * __uint_as_float(ua & 0xffff0000u);
    acc0[1] += vb * __uint_as_float(ub << 16);
    acc1[1] += vb * __uint_as_float(ub & 0xffff0000u);
  }
  if (e < end) {
    uint2 ea = cv[e];
    unsigned ua = Wbf[(size_t)(ea.x & CMASK) * 64 + lane];
    float va = __uint_as_float(ea.y);
    acc0[2] += va * __uint_as_float(ua << 16);
    acc1[2] += va * __uint_as_float(ua & 0xffff0000u);
  }
  float o0 = ((acc0[0] + acc0[1]) + (acc0[2] + acc0[3])) +
             ((acc0[4] + acc0[5]) + (acc0[6] + acc0[7]));
  float o1 = ((acc1[0] + acc1[1]) + (acc1[2] + acc1[3])) +
             ((acc1[4] + acc1[5]) + (acc1[6] + acc1[7]));
  xw[(size_t)r * 64 + lane] = f2bf(o0) | (f2bf(o1) << 16);
}

// out[r] = relu( sum_e val_e * xw[col_e] )  (xw bf16-packed, out fp32)
__global__ __launch_bounds__(256) void pull_a(
    const int* __restrict__ rowptr, const uint2* __restrict__ cv,
    const unsigned* __restrict__ xw, float2* __restrict__ out, int nrows) {
  int lane = threadIdx.x & 63;
  int r = blockIdx.x * 4 + (threadIdx.x >> 6);
  if (r >= nrows) return;
  int e = rowptr[r], end = rowptr[r + 1];
  float acc0[8], acc1[8];
#pragma unroll
  for (int u = 0; u < 8; ++u) { acc0[u] = 0.f; acc1[u] = 0.f; }
  for (; e + 7 < end; e += 8) {
    uint2 ed[8]; unsigned xg[8];
#pragma unroll
    for (int u = 0; u < 8; ++u) ed[u] = cv[e + u];
#pragma unroll
    for (int u = 0; u < 8; ++u)
      xg[u] = xw[(size_t)(ed[u].x & CMASK) * 64 + lane];
#pragma unroll
    for (int u = 0; u < 8; ++u) {
      float v = __uint_as_float(ed[u].y);
      acc0[u] += v * __uint_as_float(xg[u] << 16);
      acc1[u] += v * __uint_as_float(xg[u] & 0xffff0000u);
    }
  }
  for (; e + 1 < end; e += 2) {
    uint2 ea = cv[e], eb = cv[e + 1];
    unsigned ua = xw[(size_t)(ea.x & CMASK) * 64 + lane];
    unsigned ub = xw[(size_t)(eb.x & CMASK) * 64 + lane];
    float va = __uint_as_float(ea.y), vb = __uint_as_float(eb.y);
    acc0[0] += va * __uint_as_float(ua << 16);
    acc1[0] += va * __uint_as_float(ua & 0xffff0000u);
    acc0[1] += vb * __uint_as_float(ub << 16);
    acc1[1] += vb * __uint_as_float(ub & 0xffff0000u);
  }
  if (e < end) {
    uint2 ea = cv[e];
    unsigned ua = xw[(size_t)(ea.x & CMASK) * 64 + lane];
    float va = __uint_as_float(ea.y);
    acc0[2] += va * __uint_as_float(ua << 16);
    acc1[2] += va * __uint_as_float(ua & 0xffff0000u);
  }
  float o0 = ((acc0[0] + acc0[1]) + (acc0[2] + acc0[3])) +
             ((acc0[4] + acc0[5]) + (acc0[6] + acc0[7]));
  float o1 = ((acc1[0] + acc1[1]) + (acc1[2] + acc1[3])) +
             ((acc1[4] + acc1[5]) + (acc1[6] + acc1[7]));
  out[(size_t)r * 64 + lane] = make_float2(fmaxf(o0, 0.f), fmaxf(o1, 0.f));
}

// ---------------- fallback (atomic push) ----------------

__global__ __launch_bounds__(256) void spmm_scatter(
    const int* __restrict__ rows, const int* __restrict__ cols,
    const float* __restrict__ vals, const float* __restrict__ B,
    float* __restrict__ out, int nnz) {
  int e = blockIdx.x * 2 + (threadIdx.x >> 7);
  int d = threadIdx.x & (ODIM - 1);
  if (e >= nnz) return;
  atomicAdd(&out[(size_t)rows[e] * ODIM + d],
            vals[e] * B[(size_t)cols[e] * ODIM + d]);
}

__global__ __launch_bounds__(256) void relu_inplace(float* __restrict__ p, long n4) {
  long i = (long)blockIdx.x * blockDim.x + threadIdx.x;
  long stride = (long)gridDim.x * blockDim.x;
  float4* p4 = (float4*)p;
  for (long j = i; j < n4; j += stride) {
    float4 v = p4[j];
    v.x = fmaxf(v.x, 0.f); v.y = fmaxf(v.y, 0.f);
    v.z = fmaxf(v.z, 0.f); v.w = fmaxf(v.w, 0.f);
    p4[j] = v;
  }
}

extern "C" void kernel_launch(void* const* d_in, const int* in_sizes, int n_in,
                              void* d_out, int out_size, void* d_ws, size_t ws_size,
                              hipStream_t stream) {
  const int*   x_rows   = (const int*)d_in[0];
  const int*   x_cols   = (const int*)d_in[1];
  const float* x_vals   = (const float*)d_in[2];
  const int*   adj_rows = (const int*)d_in[3];
  const int*   adj_cols = (const int*)d_in[4];
  const float* adj_vals = (const float*)d_in[5];
  const float* W        = (const float*)d_in[6];

  const int nnz_x   = in_sizes[0];
  const int nnz_adj = in_sizes[3];
  const int wlen    = in_sizes[6];              // IN_DIM * ODIM
  const int N       = out_size / ODIM;          // 50000
  const int NB      = (N + BROWS - 1) / BROWS;  // 391
  const int ntX     = (nnz_x + TILE - 1) / TILE;
  const int ntA     = (nnz_adj + TILE - 1) / TILE;
  const int wwords  = wlen / 2;                 // packed bf16 words

  float* out = (float*)d_out;

  // Common control block
  char* p = (char*)d_ws;
  int* ghX   = (int*)p;  p += NBMAX * sizeof(int);
  int* ghA   = (int*)p;  p += NBMAX * sizeof(int);        // adjacent: one memset
  int* baseX = (int*)p;  p += (NBMAX + 1) * sizeof(int);
  int* baseA = (int*)p;  p += (NBMAX + 1) * sizeof(int);
  int* curX  = (int*)p;  p += NBMAX * sizeof(int);
  int* curA  = (int*)p;  p += NBMAX * sizeof(int);
  int* rpX   = (int*)p;  p += (size_t)(N + 1) * sizeof(int);
  int* rpA   = (int*)p;  p += (size_t)(N + 1) * sizeof(int);
  p = (char*)(((uintptr_t)p + 255) & ~(uintptr_t)255);
  u32* Wbf   = (u32*)p;  p += (size_t)wwords * sizeof(u32);
  p = (char*)(((uintptr_t)p + 255) & ~(uintptr_t)255);
  char* bufs = p;

  const size_t xw_bytes = (size_t)N * 64 * sizeof(u32);

  // --- Fused layout: separate ping buffers for X and A (one partition launch).
  // xw aliases bufPX..bufPA (dead after bucket_sort_both).
  {
    char* q = bufs;
    uint2* bufPX = (uint2*)q; q += (size_t)nnz_x * sizeof(uint2);
    uint2* bufPA = (uint2*)q; q += (size_t)nnz_adj * sizeof(uint2);
    uint2* bufSX = (uint2*)q; q += (size_t)nnz_x * sizeof(uint2);
    uint2* bufSA = (uint2*)q; q += (size_t)nnz_adj * sizeof(uint2);
    size_t need = (size_t)(q - (char*)d_ws);
    bool xw_fits = xw_bytes <= ((size_t)nnz_x + nnz_adj) * sizeof(uint2);
    if (ws_size >= need && NB <= NBMAX && xw_fits) {
      u32* xw = (u32*)bufPX;
      (void)hipMemsetAsync(ghX, 0, 2 * NBMAX * sizeof(int), stream);
      hist_buckets<<<1024, 256, 0, stream>>>(x_rows, nnz_x, adj_rows, nnz_adj, ghX, ghA);
      conv_w<<<(wwords + 255) / 256, 256, 0, stream>>>((const float2*)W, Wbf, wwords);
      scan_buckets<<<2, NBMAX, 0, stream>>>(ghX, baseX, curX, ghA, baseA, curA, NB);
      partition_both<<<ntX + ntA, 256, 0, stream>>>(
          x_rows, x_cols, x_vals, nnz_x, ntX, curX, bufPX,
          adj_rows, adj_cols, adj_vals, nnz_adj, curA, bufPA);
      bucket_sort_both<<<2 * NB, 256, 0, stream>>>(
          NB, baseX, bufPX, bufSX, rpX, baseA, bufPA, bufSA, rpA, N);
      pull_x<<<(N + 3) / 4, 256, 0, stream>>>(rpX, bufSX, Wbf, xw, N);
      pull_a<<<(N + 3) / 4, 256, 0, stream>>>(rpA, bufSA, xw, (float2*)out, N);
      return;
    }
  }

  // --- Sequential layout (shared ping buffer) if ws smaller.
  {
    size_t bufP_elems = (size_t)(nnz_x > nnz_adj ? nnz_x : nnz_adj);
    if (bufP_elems * sizeof(uint2) < xw_bytes)
      bufP_elems = (xw_bytes + sizeof(uint2) - 1) / sizeof(uint2);
    char* q = bufs;
    uint2* bufP  = (uint2*)q; q += bufP_elems * sizeof(uint2);
    uint2* bufSX = (uint2*)q; q += (size_t)nnz_x * sizeof(uint2);
    uint2* bufSA = (uint2*)q; q += (size_t)nnz_adj * sizeof(uint2);
    size_t need = (size_t)(q - (char*)d_ws);
    if (ws_size >= need && NB <= NBMAX) {
      u32* xw = (u32*)bufP;
      (void)hipMemsetAsync(ghX, 0, 2 * NBMAX * sizeof(int), stream);
      hist_buckets<<<1024, 256, 0, stream>>>(x_rows, nnz_x, adj_rows, nnz_adj, ghX, ghA);
      conv_w<<<(wwords + 255) / 256, 256, 0, stream>>>((const float2*)W, Wbf, wwords);
      scan_buckets<<<2, NBMAX, 0, stream>>>(ghX, baseX, curX, ghA, baseA, curA, NB);
      partition_both<<<ntX, 256, 0, stream>>>(
          x_rows, x_cols, x_vals, nnz_x, ntX, curX, bufP,
          adj_rows, adj_cols, adj_vals, nnz_adj, curA, bufP);
      bucket_sort_both<<<NB, 256, 0, stream>>>(
          NB, baseX, bufP, bufSX, rpX, baseA, bufP, bufSA, rpA, N);
      partition_both<<<ntA, 256, 0, stream>>>(
          x_rows, x_cols, x_vals, nnz_x, 0, curX, bufP,
          adj_rows, adj_cols, adj_vals, nnz_adj, curA, bufP);
      bucket_sort_both<<<NB, 256, 0, stream>>>(
          0, baseX, bufP, bufSX, rpX, baseA, bufP, bufSA, rpA, N);
      pull_x<<<(N + 3) / 4, 256, 0, stream>>>(rpX, bufSX, Wbf, xw, N);
      pull_a<<<(N + 3) / 4, 256, 0, stream>>>(rpA, bufSA, xw, (float2*)out, N);
      return;
    }
  }

  // --- Last resort: atomic push (needs only N*ODIM floats).
  {
    float* xwf = (float*)d_ws;
    const size_t out_bytes = (size_t)out_size * sizeof(float);
    (void)hipMemsetAsync(xwf, 0, out_bytes, stream);
    (void)hipMemsetAsync(out, 0, out_bytes, stream);
    spmm_scatter<<<(nnz_x + 1) / 2, 256, 0, stream>>>(x_rows, x_cols, x_vals, W, xwf, nnz_x);
    spmm_scatter<<<(nnz_adj + 1) / 2, 256, 0, stream>>>(adj_rows, adj_cols, adj_vals, xwf, out, nnz_adj);
    relu_inplace<<<2048, 256, 0, stream>>>(out, (long)out_size / 4);
  }
}